// Round 12
// baseline (7595.063 us; speedup 1.0000x reference)
//
#include <hip/hip_runtime.h>
#include <hip/hip_fp16.h>

#define DM   256      // d_model
#define DI   512      // d_inner
#define TG   768      // 3*d_model
#define TSEQ 4096
#define NB   8
#define MTOT (NB*TSEQ) // 32768

typedef _Float16 f16x4 __attribute__((ext_vector_type(4)));
typedef _Float16 f16x8 __attribute__((ext_vector_type(8)));
typedef float    f32x4 __attribute__((ext_vector_type(4)));

// ---------------- Phase 1: tiled fp32 GEMM, C = act(A @ W^T + bias) in fp16 ----
template<bool A_HALF, bool GELU_ACT, bool TNB_OUT>
__global__ __launch_bounds__(256) void gemm_bias(
    const void* __restrict__ Ap, const float* __restrict__ W,
    const float* __restrict__ bias, __half* __restrict__ C,
    int M, int N, int K)
{
  __shared__ float As[16][132];
  __shared__ float Ws[16][132];
  const int tid = threadIdx.x;
  const int tx = tid & 15, ty = tid >> 4;
  const int m0 = blockIdx.y * 128;
  const int n0 = blockIdx.x * 128;

  float acc[8][8] = {};

  for (int k0 = 0; k0 < K; k0 += 16) {
    if constexpr (A_HALF) {
      const __half* A = (const __half*)Ap;
      int r = tid >> 1, seg = (tid & 1) * 8;
      float4 raw = *(const float4*)(A + (size_t)(m0 + r) * K + k0 + seg);
      const __half* hv = (const __half*)&raw;
      #pragma unroll
      for (int q = 0; q < 8; q++) As[seg + q][r] = __half2float(hv[q]);
    } else {
      const float* A = (const float*)Ap;
      #pragma unroll
      for (int rep = 0; rep < 2; rep++) {
        int r = (tid >> 2) + rep * 64;
        int seg = (tid & 3) * 4;
        float4 v = *(const float4*)(A + (size_t)(m0 + r) * K + k0 + seg);
        As[seg + 0][r] = v.x; As[seg + 1][r] = v.y;
        As[seg + 2][r] = v.z; As[seg + 3][r] = v.w;
      }
    }
    #pragma unroll
    for (int rep = 0; rep < 2; rep++) {
      int r = (tid >> 2) + rep * 64;
      int seg = (tid & 3) * 4;
      float4 v = *(const float4*)(W + (size_t)(n0 + r) * K + k0 + seg);
      Ws[seg + 0][r] = v.x; Ws[seg + 1][r] = v.y;
      Ws[seg + 2][r] = v.z; Ws[seg + 3][r] = v.w;
    }
    __syncthreads();
    #pragma unroll
    for (int kk = 0; kk < 16; ++kk) {
      float a[8], b[8];
      *(float4*)&a[0] = *(const float4*)&As[kk][ty * 8];
      *(float4*)&a[4] = *(const float4*)&As[kk][ty * 8 + 4];
      *(float4*)&b[0] = *(const float4*)&Ws[kk][tx * 8];
      *(float4*)&b[4] = *(const float4*)&Ws[kk][tx * 8 + 4];
      #pragma unroll
      for (int i = 0; i < 8; i++)
        #pragma unroll
        for (int j = 0; j < 8; j++)
          acc[i][j] += a[i] * b[j];
    }
    __syncthreads();
  }

  #pragma unroll
  for (int i = 0; i < 8; i++) {
    int m = m0 + ty * 8 + i;
    #pragma unroll
    for (int j = 0; j < 8; j++) {
      int n = n0 + tx * 8 + j;
      float v = acc[i][j] + bias[n];
      if constexpr (GELU_ACT) {
        v = 0.5f * v * (1.0f + erff(v * 0.70710678118654752f));
      }
      if constexpr (TNB_OUT) {
        C[((size_t)(m & (TSEQ - 1)) * TG + n) * NB + (m >> 12)] = __float2half(v);
      } else {
        C[(size_t)m * N + n] = __float2half(v);
      }
    }
  }
}

// ---------------- helpers ---------------------------------------------------
#define MFMA16(A, B, C) __builtin_amdgcn_mfma_f32_16x16x32_f16(A, B, C, 0, 0, 0)

__device__ __forceinline__ void gload_lds(const void* g, void* l) {
  __builtin_amdgcn_global_load_lds(
      (const __attribute__((address_space(1))) unsigned int*)g,
      (__attribute__((address_space(3))) unsigned int*)l, 4, 0, 0);
}

__device__ __forceinline__ float selswap(float x, float y, int lane) {
  float ys = __shfl(y, lane ^ 32, 64);
  return (lane < 32) ? x : ys;
}

#define LDB(NM, G, C, KT) f16x8 NM; { \
    const float* p_ = Whh + (size_t)(256*(G) + 16*((C)*8 + w) + col) * DM + (KT)*32 + kgrp*8; \
    float4 fa_ = *(const float4*)p_; float4 fb_ = *(const float4*)(p_ + 4);    \
    NM[0]=(_Float16)fa_.x; NM[1]=(_Float16)fa_.y; NM[2]=(_Float16)fa_.z; NM[3]=(_Float16)fa_.w; \
    NM[4]=(_Float16)fb_.x; NM[5]=(_Float16)fb_.y; NM[6]=(_Float16)fb_.z; NM[7]=(_Float16)fb_.w; }

#define LDB7(P, G, C) \
  LDB(P##0, G, C, 0) LDB(P##1, G, C, 1) LDB(P##2, G, C, 2) LDB(P##3, G, C, 3) \
  LDB(P##4, G, C, 4) LDB(P##5, G, C, 5) LDB(P##6, G, C, 6)

#define KSTEP(KT, BR0, BZ0, BN0, BR1, BZ1, BN1) {                              \
    f16x8 a_ = *(const f16x8*)(hp + (KT)*64);                                  \
    R0 = MFMA16(a_, BR0, R0); Z0 = MFMA16(a_, BZ0, Z0); N0 = MFMA16(a_, BN0, N0); \
    R1 = MFMA16(a_, BR1, R1); Z1 = MFMA16(a_, BZ1, Z1); N1 = MFMA16(a_, BN1, N1); }

// ---------------- Phase 2: GRU scan via MFMA, one block, all 8 batches -------
// ROUND-11 LESSON: B-frags weren't register-resident (LDS 16.9KB -> multi-block
// occupancy target -> 128-reg/wave budget) and were re-streamed from L2 every
// step: 393KB / ~256B/cyc ~= 1536 cyc = the observed MFMA phase. Fix package:
// 96KB LDS pool (1 block/CU -> 256 regs/wave), B-frags pinned to AGPR class
// via empty asm "+a" (MFMA reads AGPRs natively), K-tile 7 streamed from LDS
// (fits 168 AGPR + ~70 arch <= 256), gx staged to LDS with global_load_lds
// (frees ~24 arch regs; latency hidden under the step, drained by the step
// barrier).
__global__ __attribute__((amdgpu_flat_work_group_size(512, 512)))
void gru_scan(
    const __half* __restrict__ gxb,  // [T][768][8] f16 (includes b_ih)
    const float*  __restrict__ Whh,  // [768, 256]
    const float*  __restrict__ bhh,  // [768]
    float* __restrict__ out)         // [B, T, 256]
{
  const int tid  = threadIdx.x;
  const int w    = tid >> 6;
  const int lane = tid & 63;
  const int col  = lane & 15;
  const int kgrp = lane >> 4;
  const int ch   = lane >> 5;
  const int bb   = ((lane >> 4) & 1) * 4;

  // pool (halves): hb[2][16][264] = [0,8448) | gx[2][6144] = [8448,20736)
  //                | W_kt7[768][32] = [20736,45312) ; declared 49152 -> 96KB
  __shared__ __align__(16) _Float16 pool[49152];

  for (int i = tid; i < 8448; i += 512) pool[i] = (_Float16)0.0f;
  for (int idx = tid; idx < 768 * 32; idx += 512) {
    int un = idx >> 5, k = idx & 31;
    pool[20736 + un * 32 + k] = (_Float16)Whh[(size_t)un * DM + 224 + k];
  }

  // ---- resident B-fragments: 42 x f16x8 (K-tiles 0..6), pinned to AGPR ----
  LDB7(bR0_, 0, 0) LDB7(bZ0_, 1, 0) LDB7(bN0_, 2, 0)
  LDB7(bR1_, 0, 1) LDB7(bZ1_, 1, 1) LDB7(bN1_, 2, 1)
  asm volatile("" : "+a"(bR0_0), "+a"(bR0_1), "+a"(bR0_2), "+a"(bR0_3), "+a"(bR0_4), "+a"(bR0_5), "+a"(bR0_6));
  asm volatile("" : "+a"(bZ0_0), "+a"(bZ0_1), "+a"(bZ0_2), "+a"(bZ0_3), "+a"(bZ0_4), "+a"(bZ0_5), "+a"(bZ0_6));
  asm volatile("" : "+a"(bN0_0), "+a"(bN0_1), "+a"(bN0_2), "+a"(bN0_3), "+a"(bN0_4), "+a"(bN0_5), "+a"(bN0_6));
  asm volatile("" : "+a"(bR1_0), "+a"(bR1_1), "+a"(bR1_2), "+a"(bR1_3), "+a"(bR1_4), "+a"(bR1_5), "+a"(bR1_6));
  asm volatile("" : "+a"(bZ1_0), "+a"(bZ1_1), "+a"(bZ1_2), "+a"(bZ1_3), "+a"(bZ1_4), "+a"(bZ1_5), "+a"(bZ1_6));
  asm volatile("" : "+a"(bN1_0), "+a"(bN1_1), "+a"(bN1_2), "+a"(bN1_3), "+a"(bN1_4), "+a"(bN1_5), "+a"(bN1_6));

  const int u = 16 * (w + 8 * ch) + col;
  const float brv = bhh[u];
  const float bzv = bhh[DM + u];
  const float bnv = bhh[2 * DM + u];
  float hl0 = 0.f, hl1 = 0.f, hl2 = 0.f, hl3 = 0.f;

  // stage gx for t=0 into buf0
  {
    const __half* s = gxb + (size_t)w * 768 + lane * 2;
    _Float16* d = &pool[8448 + w * 768];
    gload_lds(s, d); gload_lds(s + 128, d + 128); gload_lds(s + 256, d + 256);
    gload_lds(s + 384, d + 384); gload_lds(s + 512, d + 512); gload_lds(s + 640, d + 640);
  }
  __syncthreads();

  const char* hbase  = (const char*)pool + col * 528 + kgrp * 16;
  const char* gbase  = (const char*)pool + 16896 + u * 16 + bb * 2;
  char*       hwbase = (char*)pool + bb * 528 + u * 2;
  const char* wl     = (const char*)pool + 41472 + (16 * w + col) * 64 + kgrp * 16;

  for (int t = 0; t < TSEQ; ++t) {
    const int cur = t & 1, nxt = cur ^ 1;

    // 1) stage gx(t+1) into buf nxt (drained by this step's end barrier)
    {
      int ts = (t + 1 < TSEQ) ? t + 1 : t;
      const __half* s = gxb + (size_t)ts * 6144 + w * 768 + lane * 2;
      _Float16* d = &pool[8448 + nxt * 6144 + w * 768];
      gload_lds(s, d); gload_lds(s + 128, d + 128); gload_lds(s + 256, d + 256);
      gload_lds(s + 384, d + 384); gload_lds(s + 512, d + 512); gload_lds(s + 640, d + 640);
    }

    // 2) MFMA: gh[8,768] = h[8,256] @ W_hh^T  (48 MFMA/wave)
    const char* hp = hbase + cur * 8448;
    const f32x4 Zv = {0.f, 0.f, 0.f, 0.f};
    f32x4 R0 = Zv, Z0 = Zv, N0 = Zv, R1 = Zv, Z1 = Zv, N1 = Zv;
    KSTEP(0, bR0_0, bZ0_0, bN0_0, bR1_0, bZ1_0, bN1_0)
    KSTEP(1, bR0_1, bZ0_1, bN0_1, bR1_1, bZ1_1, bN1_1)
    KSTEP(2, bR0_2, bZ0_2, bN0_2, bR1_2, bZ1_2, bN1_2)
    KSTEP(3, bR0_3, bZ0_3, bN0_3, bR1_3, bZ1_3, bN1_3)
    KSTEP(4, bR0_4, bZ0_4, bN0_4, bR1_4, bZ1_4, bN1_4)
    KSTEP(5, bR0_5, bZ0_5, bN0_5, bR1_5, bZ1_5, bN1_5)
    KSTEP(6, bR0_6, bZ0_6, bN0_6, bR1_6, bZ1_6, bN1_6)
    {   // K-tile 7: B from LDS
      f16x8 a_ = *(const f16x8*)(hp + 7 * 64);
      f16x8 t0 = *(const f16x8*)(wl);
      f16x8 t1 = *(const f16x8*)(wl + 8192);
      R0 = MFMA16(a_, t0, R0); R1 = MFMA16(a_, t1, R1);
      f16x8 t2 = *(const f16x8*)(wl + 16384);
      f16x8 t3 = *(const f16x8*)(wl + 24576);
      Z0 = MFMA16(a_, t2, Z0); Z1 = MFMA16(a_, t3, Z1);
      f16x8 t4 = *(const f16x8*)(wl + 32768);
      f16x8 t5 = *(const f16x8*)(wl + 40960);
      N0 = MFMA16(a_, t4, N0); N1 = MFMA16(a_, t5, N1);
    }

    // 3) gates (gx from LDS buf cur; staged last step, drained by last barrier)
    const char* gl = gbase + cur * 12288;
    f16x4 gr4 = *(const f16x4*)(gl);
    f16x4 gz4 = *(const f16x4*)(gl + 4096);
    f16x4 gn4 = *(const f16x4*)(gl + 8192);
    char* hw = hwbase + nxt * 8448;

    #define GATE(i, HL) {                                                      \
      float ghr = selswap(R0[i], R1[i], lane);                                 \
      float ghz = selswap(Z0[i], Z1[i], lane);                                 \
      float ghn = selswap(N0[i], N1[i], lane);                                 \
      float xr = (float)gr4[i], xz = (float)gz4[i], xn = (float)gn4[i];        \
      float rg = __builtin_amdgcn_rcpf(1.0f + __expf(-(xr + ghr + brv)));      \
      float zg = __builtin_amdgcn_rcpf(1.0f + __expf(-(xz + ghz + bzv)));      \
      float ap = xn + rg * (ghn + bnv);                                        \
      float e  = __expf(-2.0f * __builtin_fabsf(ap));                          \
      float nn2 = __builtin_copysignf(                                         \
          (1.0f - e) * __builtin_amdgcn_rcpf(1.0f + e), ap);                   \
      float hnew = nn2 + zg * (HL - nn2);                                      \
      HL = hnew;                                                               \
      *(_Float16*)(hw + (i) * 528) = (_Float16)hnew;                           \
      out[((size_t)(bb + (i)) * TSEQ + t) * DM + u] = hnew;                    \
    }
    GATE(0, hl0) GATE(1, hl1) GATE(2, hl2) GATE(3, hl3)
    #undef GATE

    __syncthreads();
  }
}

extern "C" void kernel_launch(void* const* d_in, const int* in_sizes, int n_in,
                              void* d_out, int out_size, void* d_ws, size_t ws_size,
                              hipStream_t stream) {
  const float* x   = (const float*)d_in[0];
  const float* W1  = (const float*)d_in[1];
  const float* b1  = (const float*)d_in[2];
  const float* Wih = (const float*)d_in[3];
  const float* bih = (const float*)d_in[4];
  const float* Whh = (const float*)d_in[5];
  const float* bhh = (const float*)d_in[6];
  float* out = (float*)d_out;

  char* ws = (char*)d_ws;
  __half* h  = (__half*)ws;                                   // [32768,512] fp16
  size_t h_bytes = (size_t)MTOT * DI * sizeof(__half);
  h_bytes = (h_bytes + 255) & ~(size_t)255;
  __half* gxbuf = (__half*)(ws + h_bytes);                    // [T][768][8] fp16

  dim3 blk(256);
  gemm_bias<false, true, false><<<dim3(DI / 128, MTOT / 128), blk, 0, stream>>>(
      x, W1, b1, h, MTOT, DI, DM);
  gemm_bias<true, false, true><<<dim3(TG / 128, MTOT / 128), blk, 0, stream>>>(
      h, Wih, bih, gxbuf, MTOT, TG, DI);
  gru_scan<<<1, 512, 0, stream>>>(gxbuf, Whh, bhh, out);
}

// Round 13
// 5603.022 us; speedup vs baseline: 1.3555x; 1.3555x over previous
//
#include <hip/hip_runtime.h>
#include <hip/hip_fp16.h>

#define DM   256      // d_model
#define DI   512      // d_inner
#define TG   768      // 3*d_model
#define TSEQ 4096
#define NB   8
#define MTOT (NB*TSEQ) // 32768

typedef _Float16 h2f   __attribute__((ext_vector_type(2)));
typedef _Float16 f16x8 __attribute__((ext_vector_type(8)));

// ---------------- Phase 1: tiled fp32 GEMM, C = act(A @ W^T + bias) in fp16 ----
template<bool A_HALF, bool GELU_ACT>
__global__ __launch_bounds__(256) void gemm_bias(
    const void* __restrict__ Ap, const float* __restrict__ W,
    const float* __restrict__ bias, __half* __restrict__ C,
    int M, int N, int K)
{
  __shared__ float As[16][132];
  __shared__ float Ws[16][132];
  const int tid = threadIdx.x;
  const int tx = tid & 15, ty = tid >> 4;
  const int m0 = blockIdx.y * 128;
  const int n0 = blockIdx.x * 128;

  float acc[8][8] = {};

  for (int k0 = 0; k0 < K; k0 += 16) {
    if constexpr (A_HALF) {
      const __half* A = (const __half*)Ap;
      int r = tid >> 1, seg = (tid & 1) * 8;
      float4 raw = *(const float4*)(A + (size_t)(m0 + r) * K + k0 + seg);
      const __half* hv = (const __half*)&raw;
      #pragma unroll
      for (int q = 0; q < 8; q++) As[seg + q][r] = __half2float(hv[q]);
    } else {
      const float* A = (const float*)Ap;
      #pragma unroll
      for (int rep = 0; rep < 2; rep++) {
        int r = (tid >> 2) + rep * 64;
        int seg = (tid & 3) * 4;
        float4 v = *(const float4*)(A + (size_t)(m0 + r) * K + k0 + seg);
        As[seg + 0][r] = v.x; As[seg + 1][r] = v.y;
        As[seg + 2][r] = v.z; As[seg + 3][r] = v.w;
      }
    }
    #pragma unroll
    for (int rep = 0; rep < 2; rep++) {
      int r = (tid >> 2) + rep * 64;
      int seg = (tid & 3) * 4;
      float4 v = *(const float4*)(W + (size_t)(n0 + r) * K + k0 + seg);
      Ws[seg + 0][r] = v.x; Ws[seg + 1][r] = v.y;
      Ws[seg + 2][r] = v.z; Ws[seg + 3][r] = v.w;
    }
    __syncthreads();
    #pragma unroll
    for (int kk = 0; kk < 16; ++kk) {
      float a[8], b[8];
      *(float4*)&a[0] = *(const float4*)&As[kk][ty * 8];
      *(float4*)&a[4] = *(const float4*)&As[kk][ty * 8 + 4];
      *(float4*)&b[0] = *(const float4*)&Ws[kk][tx * 8];
      *(float4*)&b[4] = *(const float4*)&Ws[kk][tx * 8 + 4];
      #pragma unroll
      for (int i = 0; i < 8; i++)
        #pragma unroll
        for (int j = 0; j < 8; j++)
          acc[i][j] += a[i] * b[j];
    }
    __syncthreads();
  }

  #pragma unroll
  for (int i = 0; i < 8; i++) {
    int m = m0 + ty * 8 + i;
    #pragma unroll
    for (int j = 0; j < 8; j++) {
      int n = n0 + tx * 8 + j;
      float v = acc[i][j] + bias[n];
      if constexpr (GELU_ACT) {
        v = 0.5f * v * (1.0f + erff(v * 0.70710678118654752f));
      }
      C[(size_t)m * N + n] = __float2half(v);
    }
  }
}

// ---------------- DPP quad butterflies (VALU only) ---------------------------
__device__ __forceinline__ float dpp_xor1_add(float v) {
  int i = __builtin_bit_cast(int, v);
  int s = __builtin_amdgcn_update_dpp(i, i, 0xB1, 0xF, 0xF, true); // [1,0,3,2]
  return v + __builtin_bit_cast(float, s);
}
__device__ __forceinline__ float dpp_xor2_add(float v) {
  int i = __builtin_bit_cast(int, v);
  int s = __builtin_amdgcn_update_dpp(i, i, 0x4E, 0xF, 0xF, true); // [2,3,0,1]
  return v + __builtin_bit_cast(float, s);
}

// ---- 96 named h2f weight locals: 32 per gate (this lane's 64-col slice) ----
#define DW(i) h2f wr##i, wz##i, wn##i;
#define LW(i) { float2 f_;                                                     \
    f_ = *(const float2*)(rr + 2*(i)); wr##i[0]=(_Float16)f_.x; wr##i[1]=(_Float16)f_.y; \
    f_ = *(const float2*)(rz + 2*(i)); wz##i[0]=(_Float16)f_.x; wz##i[1]=(_Float16)f_.y; \
    f_ = *(const float2*)(rn + 2*(i)); wn##i[0]=(_Float16)f_.x; wn##i[1]=(_Float16)f_.y; }

#define REP32(M) \
  M(0)  M(1)  M(2)  M(3)  M(4)  M(5)  M(6)  M(7)  \
  M(8)  M(9)  M(10) M(11) M(12) M(13) M(14) M(15) \
  M(16) M(17) M(18) M(19) M(20) M(21) M(22) M(23) \
  M(24) M(25) M(26) M(27) M(28) M(29) M(30) M(31)

// 12 fdot2 on one f16x8 chunk of h (cols 8B..8B+7 of this lane's slice)
#define DSTEP(B, I0, I1, I2, I3) {                                        \
    f16x8 hh_ = *(const f16x8*)(hp + (B) * 8);                            \
    h2f c0_ = __builtin_shufflevector(hh_, hh_, 0, 1);                    \
    h2f c1_ = __builtin_shufflevector(hh_, hh_, 2, 3);                    \
    h2f c2_ = __builtin_shufflevector(hh_, hh_, 4, 5);                    \
    h2f c3_ = __builtin_shufflevector(hh_, hh_, 6, 7);                    \
    ar0 = __builtin_amdgcn_fdot2(wr##I0, c0_, ar0, false);                \
    az0 = __builtin_amdgcn_fdot2(wz##I0, c0_, az0, false);                \
    an0 = __builtin_amdgcn_fdot2(wn##I0, c0_, an0, false);                \
    ar1 = __builtin_amdgcn_fdot2(wr##I1, c1_, ar1, false);                \
    az1 = __builtin_amdgcn_fdot2(wz##I1, c1_, az1, false);                \
    an1 = __builtin_amdgcn_fdot2(wn##I1, c1_, an1, false);                \
    ar0 = __builtin_amdgcn_fdot2(wr##I2, c2_, ar0, false);                \
    az0 = __builtin_amdgcn_fdot2(wz##I2, c2_, az0, false);                \
    an0 = __builtin_amdgcn_fdot2(wn##I2, c2_, an0, false);                \
    ar1 = __builtin_amdgcn_fdot2(wr##I3, c3_, ar1, false);                \
    az1 = __builtin_amdgcn_fdot2(wz##I3, c3_, az1, false);                \
    an1 = __builtin_amdgcn_fdot2(wn##I3, c3_, an1, false); }

// ---------------- Phase 2: persistent GRU scan, 1024 thr, 1 block/batch ------
// ROUNDS 4-12 LESSON: the compiler hard-caps arch VGPRs at 128/wave; nothing
// dislodges it. So fit INSIDE it: 16 waves x 128 regs = the full 512KB CU file
// holds W_hh (393KB f16). Lane-quad owns unit u=tid>>2 (all 3 gate rows);
// lane p=tid&3 owns cols [64p,64p+64) -> 96 weight regs + ~25 working < 128.
// Quad butterfly (xor1+xor2 DPP) gives all 4 lanes the full 256-wide sums;
// gates quad-redundant (no LDS exchange); biases pre-scaled x0.25 folded into
// acc init (quad sum restores them). One barrier/step, double-buffered h.
// h LDS layout [2][4][72]: 144B group stride => p-groups hit distinct bank
// quads; same-p lanes read identical addresses (broadcast, conflict-free).
__global__ __launch_bounds__(1024, 1)
void gru_scan(
    const __half* __restrict__ gx,   // [B*T, 768] f16 (includes b_ih)
    const float*  __restrict__ Whh,  // [768, 256]
    const float*  __restrict__ bhh,  // [768]
    float* __restrict__ out)         // [B, T, 256]
{
  const int b   = blockIdx.x;
  const int tid = threadIdx.x;   // 0..1023
  const int q   = tid >> 2;      // hidden unit 0..255
  const int p   = tid & 3;       // col quarter

  __shared__ __align__(16) _Float16 hbuf[2][4][72];

  // ---- weights: 3 gate rows x 64 cols -> 96 named h2f ----
  REP32(DW)
  {
    const float* rr = Whh + (size_t)q * DM + p * 64;
    const float* rz = rr + 256 * DM;
    const float* rn = rr + 512 * DM;
    REP32(LW)
  }
  const float br4 = 0.25f * bhh[q];
  const float bz4 = 0.25f * bhh[DM + q];
  const float bn4 = 0.25f * bhh[2 * DM + q];
  float hloc = 0.0f;

  if (tid < 2 * 4 * 72) ((_Float16*)hbuf)[tid] = (_Float16)0.0f;
  __syncthreads();

  const __half* g = gx + (size_t)b * TSEQ * TG + q;
  float* outb = out + (size_t)b * TSEQ * DM + q;

  __half grc = g[0], gzc = g[DM], gnc = g[2 * DM];

  for (int t = 0; t < TSEQ; ++t) {
    const int cur = t & 1, nxt = cur ^ 1;
    const _Float16* hp = &hbuf[cur][p][0];

    // prefetch next step's gx (consumed next iteration)
    int tt = (t + 1 < TSEQ) ? t + 1 : t;
    const __half* g1 = g + (size_t)tt * TG;
    __half grn = g1[0], gzn = g1[DM], gnn = g1[2 * DM];

    // ---- partial dots over this lane's 64 cols (96 fdot2) ----
    float ar0 = br4, ar1 = 0.f, az0 = bz4, az1 = 0.f, an0 = bn4, an1 = 0.f;
    DSTEP(0,  0,  1,  2,  3)  DSTEP(1,  4,  5,  6,  7)
    DSTEP(2,  8,  9, 10, 11)  DSTEP(3, 12, 13, 14, 15)
    DSTEP(4, 16, 17, 18, 19)  DSTEP(5, 20, 21, 22, 23)
    DSTEP(6, 24, 25, 26, 27)  DSTEP(7, 28, 29, 30, 31)

    // ---- quad butterfly: all 4 lanes get full 256-wide sums (+bias) ----
    float ar = dpp_xor2_add(dpp_xor1_add(ar0 + ar1));
    float az = dpp_xor2_add(dpp_xor1_add(az0 + az1));
    float an = dpp_xor2_add(dpp_xor1_add(an0 + an1));

    // ---- gates (quad-redundant; all lanes identical values) ----
    float xr = __half2float(grc), xz = __half2float(gzc), xn = __half2float(gnc);
    float rg = __builtin_amdgcn_rcpf(1.0f + __expf(-(xr + ar)));
    float zg = __builtin_amdgcn_rcpf(1.0f + __expf(-(xz + az)));
    float ap = xn + rg * an;
    float e  = __expf(-2.0f * __builtin_fabsf(ap));
    float nn = __builtin_copysignf((1.0f - e) * __builtin_amdgcn_rcpf(1.0f + e), ap);
    float hnew = nn + zg * (hloc - nn);
    hloc = hnew;

    if (p == 0) {
      hbuf[nxt][q >> 6][q & 63] = (_Float16)hnew;
      outb[(size_t)t * DM] = hnew;
    }
    __syncthreads();   // h(nxt) complete before next step reads it

    grc = grn; gzc = gzn; gnc = gnn;
  }
}

extern "C" void kernel_launch(void* const* d_in, const int* in_sizes, int n_in,
                              void* d_out, int out_size, void* d_ws, size_t ws_size,
                              hipStream_t stream) {
  const float* x   = (const float*)d_in[0];
  const float* W1  = (const float*)d_in[1];
  const float* b1  = (const float*)d_in[2];
  const float* Wih = (const float*)d_in[3];
  const float* bih = (const float*)d_in[4];
  const float* Whh = (const float*)d_in[5];
  const float* bhh = (const float*)d_in[6];
  float* out = (float*)d_out;

  char* ws = (char*)d_ws;
  __half* h  = (__half*)ws;                                   // [32768,512] fp16
  size_t h_bytes = (size_t)MTOT * DI * sizeof(__half);
  h_bytes = (h_bytes + 255) & ~(size_t)255;
  __half* gxbuf = (__half*)(ws + h_bytes);                    // [32768,768] fp16

  dim3 blk(256);
  gemm_bias<false, true><<<dim3(DI / 128, MTOT / 128), blk, 0, stream>>>(
      x, W1, b1, h, MTOT, DI, DM);
  gemm_bias<true, false><<<dim3(TG / 128, MTOT / 128), blk, 0, stream>>>(
      h, Wih, bih, gxbuf, MTOT, TG, DI);
  gru_scan<<<NB, 1024, 0, stream>>>(gxbuf, Whh, bhh, out);
}